// Round 4
// baseline (372.911 us; speedup 1.0000x reference)
//
#include <hip/hip_runtime.h>
#include <hip/hip_bf16.h>
#include <math.h>

#define BB 64
#define NN 1025
#define DD 768
#define HH 128
#define KK 256
#define TOK (BB*NN)          // 65600
#define OUT_XRED 0
#define OUT_IDX  (BB*(KK+1)*DD)            // 12,632,064
#define OUT_SC   (OUT_IDX + BB*(KK+1))     // + 16,448

typedef double f64x4 __attribute__((ext_vector_type(4)));

// ---------------- K0: convert W1 to fp64 (once per launch) ---------
__global__ __launch_bounds__(256) void k_cvtw(const float* __restrict__ w1,
                                              double* __restrict__ w1d)
{
    int i = blockIdx.x * 256 + threadIdx.x;   // grid covers 98304 exact
    w1d[i] = (double)w1[i];
}

// ---------------- K1: per-token mean / rstd in fp64 ----------------
__global__ __launch_bounds__(256) void k_stats(const float* __restrict__ x,
                                               double* __restrict__ mu,
                                               double* __restrict__ rstd)
{
    const int w    = threadIdx.x >> 6;
    const int lane = threadIdx.x & 63;
    const int tok  = blockIdx.x * 4 + w;          // 16400*4 = 65600 exact
    const float4* row = reinterpret_cast<const float4*>(x + (size_t)tok * DD);
    double s = 0.0, ss = 0.0;
    #pragma unroll
    for (int k = 0; k < 3; ++k) {
        float4 v = row[lane + 64*k];
        double a = v.x, b = v.y, c = v.z, d = v.w;
        s  += a + b + c + d;
        ss += a*a + b*b + c*c + d*d;
    }
    #pragma unroll
    for (int m = 32; m; m >>= 1) { s += __shfl_xor(s, m, 64); ss += __shfl_xor(ss, m, 64); }
    if (lane == 0) {
        double m_  = s / (double)DD;
        double var = ss / (double)DD - m_ * m_;
        mu[tok]   = m_;
        rstd[tok] = 1.0 / sqrt(var + 1e-5);
    }
}

// ---------------- K2: fused LN + GEMM (fp64 MFMA) + gelu + w2 -------
// 16-token tile, 4 waves, wave owns 32 cols. B (W1) pre-converted fp64,
// loaded global->reg one chunk ahead into alternating named buffers
// (compile-time ping-pong, no copies). A staged LDS swizzled, dbuf.
#define TW 16
#define KC 16
#define NCHUNK (DD/KC)
__global__ __launch_bounds__(256) void k_mlp(const float* __restrict__ x,
    const float* __restrict__ lnw, const float* __restrict__ lnb,
    const double* __restrict__ w1d, const float* __restrict__ b1,
    const float* __restrict__ w2,  const float* __restrict__ b2,
    const double* __restrict__ mu, const double* __restrict__ rstd,
    double* __restrict__ sc, float* __restrict__ scores_out)
{
    __shared__ double xs[2][KC][TW];   // 4 KB, swizzled col = t ^ k
    __shared__ double part[4][TW];

    const int tid  = threadIdx.x;
    const int wave = tid >> 6;
    const int lane = tid & 63;
    const int g    = lane >> 4;         // k-subrow 0..3
    const int t16  = lane & 15;
    const int tok0 = blockIdx.x * TW;   // grid = 4100 exact
    const int colbase = wave * 32;

    const int stok = tid >> 4;          // 0..15
    const int sk   = tid & 15;          // 0..15
    const double smu = mu[tok0 + stok];
    const double srs = rstd[tok0 + stok];
    const float* srow = x + (size_t)(tok0 + stok) * DD;

    const double* wp = w1d + (size_t)g * HH + colbase + t16;

    f64x4 accA = {0.0, 0.0, 0.0, 0.0};
    f64x4 accB = {0.0, 0.0, 0.0, 0.0};

    double bfA[8], bfB[8];

    // ---- prologue: B-frags chunk 0 + stage x chunk 0 ----
    #pragma unroll
    for (int kk = 0; kk < 4; ++kk) {
        bfA[kk*2+0] = wp[(kk*4)*HH];
        bfA[kk*2+1] = wp[(kk*4)*HH + 16];
    }
    {
        float xv = srow[sk];
        float lw = lnw[sk], lbv = lnb[sk];
        xs[0][sk][stok ^ sk] = ((double)xv - smu) * srs * (double)lw + (double)lbv;
    }
    __syncthreads();

    #define CHUNK_BODY(C, CUR, BF, BFN)                                          \
    {                                                                            \
        const int cn = (C) + 1;                                                  \
        float xvn = 0.f, lwn = 0.f, lbn = 0.f;                                   \
        if (cn < NCHUNK) {                                                       \
            const double* wpn = wp + (size_t)cn * KC * HH;                       \
            _Pragma("unroll")                                                    \
            for (int kk = 0; kk < 4; ++kk) {                                     \
                BFN[kk*2+0] = wpn[(kk*4)*HH];                                    \
                BFN[kk*2+1] = wpn[(kk*4)*HH + 16];                               \
            }                                                                    \
            xvn = srow[cn*KC + sk];                                              \
            lwn = lnw[cn*KC + sk];                                               \
            lbn = lnb[cn*KC + sk];                                               \
        }                                                                        \
        _Pragma("unroll")                                                        \
        for (int kk = 0; kk < 4; ++kk) {                                         \
            const int krow = kk*4 + g;                                           \
            double a = xs[CUR][krow][t16 ^ krow];                                \
            accA = __builtin_amdgcn_mfma_f64_16x16x4f64(a, BF[kk*2+0], accA, 0, 0, 0); \
            accB = __builtin_amdgcn_mfma_f64_16x16x4f64(a, BF[kk*2+1], accB, 0, 0, 0); \
        }                                                                        \
        if (cn < NCHUNK) {                                                       \
            xs[(CUR)^1][sk][stok ^ sk] =                                         \
                ((double)xvn - smu) * srs * (double)lwn + (double)lbn;           \
        }                                                                        \
        __syncthreads();                                                         \
    }

    for (int c = 0; c < NCHUNK; c += 2) {
        CHUNK_BODY(c,     0, bfA, bfB);
        CHUNK_BODY(c + 1, 1, bfB, bfA);
    }
    #undef CHUNK_BODY

    // epilogue: h = acc + b1; gelu exact; dot with w2; reduce
    const double b1A = (double)b1[colbase + t16];
    const double b1B = (double)b1[colbase + 16 + t16];
    const double w2A = (double)w2[colbase + t16];
    const double w2B = (double)w2[colbase + 16 + t16];
    const double is2 = 0.70710678118654752440;

    double psum[4];
    #pragma unroll
    for (int r = 0; r < 4; ++r) {
        double v0 = accA[r] + b1A;
        double v1 = accB[r] + b1B;
        double g0 = 0.5 * v0 * (1.0 + erf(v0 * is2));
        double g1 = 0.5 * v1 * (1.0 + erf(v1 * is2));
        double p = g0 * w2A + g1 * w2B;
        #pragma unroll
        for (int m = 8; m; m >>= 1) p += __shfl_xor(p, m, 64);
        psum[r] = p;
    }
    if (t16 == 0) {
        #pragma unroll
        for (int r = 0; r < 4; ++r) part[wave][g*4 + r] = psum[r];
    }
    __syncthreads();
    if (tid < TW) {
        double s = part[0][tid] + part[1][tid] + part[2][tid] + part[3][tid] + (double)b2[0];
        int tok = tok0 + tid;
        sc[tok] = s;
        scores_out[tok] = ((tok % NN) == 0) ? 1.0e9f : (float)s;
    }
}

// ---------------- K3: per-batch bitonic top-k (full 1024 sort) ------
__global__ __launch_bounds__(1024) void k_topk(const double* __restrict__ sc,
                                               float* __restrict__ idx_out)
{
    __shared__ double sk_[1024];
    __shared__ int    si[1024];
    const int tid = threadIdx.x;
    const int b   = blockIdx.x;
    sk_[tid] = sc[b*NN + 1 + tid];
    si[tid] = tid + 1;
    __syncthreads();
    for (int k = 2; k <= 1024; k <<= 1) {
        for (int j = k >> 1; j > 0; j >>= 1) {
            int ixj = tid ^ j;
            if (ixj > tid) {
                double sa = sk_[tid]; int ia = si[tid];
                double sb = sk_[ixj]; int ib = si[ixj];
                bool beforeB = (sb > sa) || (sb == sa && ib < ia);
                bool dirAsc  = ((tid & k) == 0);
                if (beforeB == dirAsc) {
                    sk_[tid] = sb; si[tid] = ib;
                    sk_[ixj] = sa; si[ixj] = ia;
                }
            }
            __syncthreads();
        }
    }
    if (tid == 0)  idx_out[b*(KK+1)] = 0.0f;
    if (tid < KK)  idx_out[b*(KK+1) + 1 + tid] = (float)si[tid];
}

// ---------------- K4: gather selected tokens ------------------------
__global__ __launch_bounds__(192) void k_gather(const float* __restrict__ x,
                                                const float* __restrict__ idx_out,
                                                float* __restrict__ xred)
{
    const int r = blockIdx.x;               // 0 .. 64*257-1
    const int b = r / (KK+1);
    const int idx = (int)(idx_out[r] + 0.5f);
    const float4* src = reinterpret_cast<const float4*>(x + ((size_t)b*NN + idx) * DD);
    float4* dst = reinterpret_cast<float4*>(xred + (size_t)r * DD);
    dst[threadIdx.x] = src[threadIdx.x];
}

extern "C" void kernel_launch(void* const* d_in, const int* in_sizes, int n_in,
                              void* d_out, int out_size, void* d_ws, size_t ws_size,
                              hipStream_t stream)
{
    const float* x   = (const float*)d_in[0];
    const float* lnw = (const float*)d_in[1];
    const float* lnb = (const float*)d_in[2];
    const float* w1  = (const float*)d_in[3];
    const float* b1  = (const float*)d_in[4];
    const float* w2  = (const float*)d_in[5];
    const float* b2  = (const float*)d_in[6];

    float* out   = (float*)d_out;
    float* xred  = out + OUT_XRED;
    float* idxf  = out + OUT_IDX;
    float* scout = out + OUT_SC;

    char* wsb = (char*)d_ws;
    double* mu   = (double*)(wsb);
    double* rstd = (double*)(wsb + (size_t)TOK*8);
    double* sc   = (double*)(wsb + (size_t)2*TOK*8);
    const size_t need = (size_t)3*TOK*8 + (size_t)DD*HH*8;
    // w1d: prefer ws; fall back to the xred region of d_out (fully
    // overwritten by k_gather afterwards) if ws is too small.
    double* w1d = (ws_size >= need) ? (double*)(wsb + (size_t)3*TOK*8)
                                    : (double*)out;

    k_cvtw  <<<DD*HH/256, 256, 0, stream>>>(w1, w1d);
    k_stats <<<TOK/4, 256, 0, stream>>>(x, mu, rstd);
    k_mlp   <<<TOK/TW, 256, 0, stream>>>(x, lnw, lnb, w1d, b1, w2, b2, mu, rstd, sc, scout);
    k_topk  <<<BB, 1024, 0, stream>>>(sc, idxf);
    k_gather<<<BB*(KK+1), 192, 0, stream>>>(x, idxf, xred);
}

// Round 5
// 133.888 us; speedup vs baseline: 2.7852x; 2.7852x over previous
//
#include <hip/hip_runtime.h>
#include <hip/hip_bf16.h>
#include <math.h>

#define BB 64
#define NN 1025
#define DD 768
#define HH 128
#define KK 256
#define TOK (BB*NN)          // 65600
#define OUT_XRED 0
#define OUT_IDX  (BB*(KK+1)*DD)            // 12,632,064
#define OUT_SC   (OUT_IDX + BB*(KK+1))     // + 16,448

typedef float    f32x4 __attribute__((ext_vector_type(4)));
typedef _Float16 f16x8 __attribute__((ext_vector_type(8)));
#define NSTEP (DD/32)        // 24 MFMA k-steps

union F16U { _Float16 h; unsigned short s; };
union FRAG { unsigned int u[4]; f16x8 v; };

// ---------------- K0: W1 -> f16, MFMA-frag-transposed layout ---------
// Wt[s][g][n][j], flat = ((s*4+g)*HH + n)*8 + j, holds W1[k= s*32+g*8+j][n]
__global__ __launch_bounds__(256) void k_cvtw(const float* __restrict__ w1,
                                              unsigned short* __restrict__ wt)
{
    int i = blockIdx.x*256 + threadIdx.x;    // 98304 exact
    int k = i >> 7, n = i & 127;
    F16U c; c.h = (_Float16)w1[i];
    int s = k >> 5, g = (k >> 3) & 3, j = k & 7;
    wt[((s*4 + g)*HH + n)*8 + j] = c.s;
}

// ---------------- K_fused: stats + LN + split-f16 MFMA + gelu + w2 ---
// 16 tokens/block, 4 waves; wave owns 32 cols (2 N-tiles).
// LDS tile xs: f32 on load (XOR-swizzled), repacked in place to
// u32 = f16(hi) | f16(lo)<<16 after stats. MFMA loop is barrier-free.
__global__ __launch_bounds__(256) void k_fused(const float* __restrict__ x,
    const float* __restrict__ lnw, const float* __restrict__ lnb,
    const unsigned short* __restrict__ wt,
    const float* __restrict__ b1, const float* __restrict__ w2,
    const float* __restrict__ b2,
    double* __restrict__ sc, float* __restrict__ scores_out)
{
    __shared__ float  xs[16*DD];        // 48 KB
    __shared__ float  mus[16], rss[16];
    __shared__ double part[4][16];

    const int tid  = threadIdx.x;
    const int wave = tid >> 6, lane = tid & 63;
    const int g    = lane >> 4, t16 = lane & 15;
    const int tok0 = blockIdx.x * 16;     // grid 4100 exact
    const int colbase = wave * 32;
    const int row = tid >> 4, l16 = tid & 15;

    // ---- phase 1: load x tile (swizzled store: f32 idx c -> c ^ ((row&7)<<2))
    {
        const float4* src = reinterpret_cast<const float4*>(x + (size_t)(tok0+row)*DD);
        const int sz = (row & 7) << 2;
        #pragma unroll
        for (int q = 0; q < 12; ++q) {
            int c4 = l16 + q*16;
            float4 v = src[c4];
            *reinterpret_cast<float4*>(&xs[row*DD + ((c4*4) ^ sz)]) = v;
        }
    }
    __syncthreads();

    // ---- phase 2: per-token mean/rstd (f64), 16 lanes per token
    {
        int tok = wave*4 + g;
        int sz = (tok & 7) << 2;
        double s = 0.0, ss = 0.0;
        #pragma unroll
        for (int j = 0; j < 48; ++j) {
            double d = xs[tok*DD + ((t16 + j*16) ^ sz)];
            s += d; ss += d*d;
        }
        #pragma unroll
        for (int m = 8; m; m >>= 1) { s += __shfl_xor(s, m, 16); ss += __shfl_xor(ss, m, 16); }
        if (t16 == 0) {
            double mu = s / 768.0, var = ss / 768.0 - mu*mu;
            mus[tok] = (float)mu;
            rss[tok] = (float)(1.0 / sqrt(var + 1e-5));
        }
    }
    __syncthreads();

    // ---- phase 3: LN + split-f16 pack, in place (each addr owned by 1 thread)
    {
        const int tok = row, sz = (tok & 7) << 2;
        const float mu = mus[tok], rs = rss[tok];
        #pragma unroll
        for (int j = 0; j < 48; ++j) {
            int c = l16 + j*16;
            int a = tok*DD + (c ^ sz);
            float xn = (xs[a] - mu) * rs * lnw[c] + lnb[c];
            F16U hi; hi.h = (_Float16)xn;
            F16U lo; lo.h = (_Float16)(xn - (float)hi.h);
            reinterpret_cast<unsigned int*>(xs)[a] =
                (unsigned int)hi.s | ((unsigned int)lo.s << 16);
        }
    }
    __syncthreads();

    // ---- phase 4: barrier-free MFMA loop (A from LDS, B from global/L2)
    const unsigned int* xu = reinterpret_cast<const unsigned int*>(xs);
    const int szA = (t16 & 7) << 2;
    const unsigned short* wtp = wt + ((size_t)g*HH + colbase + t16)*8;

    f32x4 acc0 = {0,0,0,0}, acc1 = {0,0,0,0};
    for (int s = 0; s < NSTEP; ++s) {
        const int c0 = s*32 + g*8;
        uint4 ua = *reinterpret_cast<const uint4*>(&xu[t16*DD + ( c0      ^ szA)]);
        uint4 ub = *reinterpret_cast<const uint4*>(&xu[t16*DD + ((c0 + 4) ^ szA)]);
        unsigned int u0=ua.x,u1=ua.y,u2=ua.z,u3=ua.w,u4=ub.x,u5=ub.y,u6=ub.z,u7=ub.w;
        FRAG Ah, Al;
        Ah.u[0] = (u0 & 0xffffu) | (u1 << 16);  Al.u[0] = (u0 >> 16) | (u1 & 0xffff0000u);
        Ah.u[1] = (u2 & 0xffffu) | (u3 << 16);  Al.u[1] = (u2 >> 16) | (u3 & 0xffff0000u);
        Ah.u[2] = (u4 & 0xffffu) | (u5 << 16);  Al.u[2] = (u4 >> 16) | (u5 & 0xffff0000u);
        Ah.u[3] = (u6 & 0xffffu) | (u7 << 16);  Al.u[3] = (u6 >> 16) | (u7 & 0xffff0000u);

        const f16x8 b0 = *reinterpret_cast<const f16x8*>(wtp + (size_t)s*4*HH*8);
        const f16x8 b1f = *reinterpret_cast<const f16x8*>(wtp + (size_t)s*4*HH*8 + 16*8);

        acc0 = __builtin_amdgcn_mfma_f32_16x16x32_f16(Ah.v, b0,  acc0, 0, 0, 0);
        acc0 = __builtin_amdgcn_mfma_f32_16x16x32_f16(Al.v, b0,  acc0, 0, 0, 0);
        acc1 = __builtin_amdgcn_mfma_f32_16x16x32_f16(Ah.v, b1f, acc1, 0, 0, 0);
        acc1 = __builtin_amdgcn_mfma_f32_16x16x32_f16(Al.v, b1f, acc1, 0, 0, 0);
    }

    // ---- epilogue: +b1, exact gelu (f64), dot w2, 16-lane reduce
    // lane holds D[token = g*4+r][col = colbase + t16 (+16)]
    const double b1A = (double)b1[colbase + t16];
    const double b1B = (double)b1[colbase + 16 + t16];
    const double w2A = (double)w2[colbase + t16];
    const double w2B = (double)w2[colbase + 16 + t16];
    const double is2 = 0.70710678118654752440;

    double psum[4];
    #pragma unroll
    for (int r = 0; r < 4; ++r) {
        double v0 = (double)acc0[r] + b1A;
        double v1 = (double)acc1[r] + b1B;
        double g0 = 0.5 * v0 * (1.0 + erf(v0 * is2));
        double g1 = 0.5 * v1 * (1.0 + erf(v1 * is2));
        double p = g0 * w2A + g1 * w2B;
        #pragma unroll
        for (int m = 8; m; m >>= 1) p += __shfl_xor(p, m, 64);
        psum[r] = p;
    }
    if (t16 == 0) {
        #pragma unroll
        for (int r = 0; r < 4; ++r) part[wave][g*4 + r] = psum[r];
    }
    __syncthreads();
    if (tid < 16) {
        double s = part[0][tid] + part[1][tid] + part[2][tid] + part[3][tid] + (double)b2[0];
        int tok = tok0 + tid;
        sc[tok] = s;
        scores_out[tok] = ((tok % NN) == 0) ? 1.0e9f : (float)s;
    }
}

// ---------------- K3: per-batch bitonic top-k (full 1024 sort) ------
__global__ __launch_bounds__(1024) void k_topk(const double* __restrict__ sc,
                                               float* __restrict__ idx_out)
{
    __shared__ double sk_[1024];
    __shared__ int    si[1024];
    const int tid = threadIdx.x;
    const int b   = blockIdx.x;
    sk_[tid] = sc[b*NN + 1 + tid];
    si[tid] = tid + 1;
    __syncthreads();
    for (int k = 2; k <= 1024; k <<= 1) {
        for (int j = k >> 1; j > 0; j >>= 1) {
            int ixj = tid ^ j;
            if (ixj > tid) {
                double sa = sk_[tid]; int ia = si[tid];
                double sb = sk_[ixj]; int ib = si[ixj];
                bool beforeB = (sb > sa) || (sb == sa && ib < ia);
                bool dirAsc  = ((tid & k) == 0);
                if (beforeB == dirAsc) {
                    sk_[tid] = sb; si[tid] = ib;
                    sk_[ixj] = sa; si[ixj] = ia;
                }
            }
            __syncthreads();
        }
    }
    if (tid == 0)  idx_out[b*(KK+1)] = 0.0f;
    if (tid < KK)  idx_out[b*(KK+1) + 1 + tid] = (float)si[tid];
}

// ---------------- K4: gather selected tokens ------------------------
__global__ __launch_bounds__(192) void k_gather(const float* __restrict__ x,
                                                const float* __restrict__ idx_out,
                                                float* __restrict__ xred)
{
    const int r = blockIdx.x;               // 0 .. 64*257-1
    const int b = r / (KK+1);
    const int idx = (int)(idx_out[r] + 0.5f);
    const float4* src = reinterpret_cast<const float4*>(x + ((size_t)b*NN + idx) * DD);
    float4* dst = reinterpret_cast<float4*>(xred + (size_t)r * DD);
    dst[threadIdx.x] = src[threadIdx.x];
}

extern "C" void kernel_launch(void* const* d_in, const int* in_sizes, int n_in,
                              void* d_out, int out_size, void* d_ws, size_t ws_size,
                              hipStream_t stream)
{
    const float* x   = (const float*)d_in[0];
    const float* lnw = (const float*)d_in[1];
    const float* lnb = (const float*)d_in[2];
    const float* w1  = (const float*)d_in[3];
    const float* b1  = (const float*)d_in[4];
    const float* w2  = (const float*)d_in[5];
    const float* b2  = (const float*)d_in[6];

    float* out   = (float*)d_out;
    float* xred  = out + OUT_XRED;
    float* idxf  = out + OUT_IDX;
    float* scout = out + OUT_SC;

    char* wsb = (char*)d_ws;
    double* sc          = (double*)(wsb);                       // 524,800 B
    unsigned short* wt  = (unsigned short*)(wsb + (size_t)TOK*8); // 196,608 B
    // total ws use ~0.72 MB (R1 already used 1.57 MB of ws successfully)

    k_cvtw  <<<DD*HH/256, 256, 0, stream>>>(w1, wt);
    k_fused <<<TOK/16, 256, 0, stream>>>(x, lnw, lnb, wt, b1, w2, b2, sc, scout);
    k_topk  <<<BB, 1024, 0, stream>>>(sc, idxf);
    k_gather<<<BB*(KK+1), 192, 0, stream>>>(x, idxf, xred);
}

// Round 7
// 123.091 us; speedup vs baseline: 3.0296x; 1.0877x over previous
//
#include <hip/hip_runtime.h>
#include <hip/hip_bf16.h>
#include <math.h>

#define BB 64
#define NN 1025
#define DD 768
#define HH 128
#define KK 256
#define TOK (BB*NN)          // 65600
#define OUT_XRED 0
#define OUT_IDX  (BB*(KK+1)*DD)            // 12,632,064
#define OUT_SC   (OUT_IDX + BB*(KK+1))     // + 16,448

typedef float    f32x4 __attribute__((ext_vector_type(4)));
typedef __fp16   h16x2 __attribute__((ext_vector_type(2)));
typedef _Float16 f16x8 __attribute__((ext_vector_type(8)));
#define NSTEP (DD/32)        // 24 MFMA k-steps

union U4F { uint4 u; f16x8 h; };
union H2U { h16x2 h; unsigned int u; };

// ---------------- K0: W1 -> f16, MFMA-frag-transposed layout ---------
// wt[((s*4+g)*HH + n)*8 + j] = f16(W1[k = s*32+g*8+j][n])
__global__ __launch_bounds__(256) void k_cvtw(const float* __restrict__ w1,
                                              unsigned short* __restrict__ wt)
{
    int i = blockIdx.x*256 + threadIdx.x;    // 98304 exact
    int k = i >> 7, n = i & 127;
    union { _Float16 h; unsigned short s; } c;
    c.h = (_Float16)w1[i];
    int s = k >> 5, g = (k >> 3) & 3, j = k & 7;
    wt[((s*4 + g)*HH + n)*8 + j] = c.s;
}

// ---------------- K_fused: stats + LN + split-f16 MFMA + gelu + w2 ---
// 16 tokens/block, 4 waves. Phase A: x row -> 48 regs + f64 stats.
// Phase B: LN + pkrtz split -> hi/lo u16 planes in LDS, fragment order,
// row-XOR-swizzled. Phase C: ds_read_b128 -> MFMA (no repack). f32 gelu.
__global__ __launch_bounds__(256) void k_fused(const float* __restrict__ x,
    const float* __restrict__ lnw, const float* __restrict__ lnb,
    const unsigned short* __restrict__ wt,
    const float* __restrict__ b1, const float* __restrict__ w2,
    const float* __restrict__ b2,
    double* __restrict__ sc, float* __restrict__ scores_out)
{
    __shared__ uint4 planes[2*16*96];   // hi plane [0,1536), lo plane [1536,3072) : 48 KB
    __shared__ float part[4][16];

    const int tid  = threadIdx.x;
    const int wave = tid >> 6, lane = tid & 63;
    const int g    = lane >> 4, t16 = lane & 15;
    const int t7   = t16 & 7;
    const int tok0 = blockIdx.x * 16;     // grid 4100 exact
    const int colbase = wave * 32;
    const int row = tid >> 4, l16 = tid & 15;

    // ---- phase A: load row into regs (6 groups of 8 consecutive floats), f64 stats
    const float4* srow4 = reinterpret_cast<const float4*>(x + (size_t)(tok0 + row) * DD);
    float4 xa[6], xb[6];
    double s_ = 0.0, ss = 0.0;
    #pragma unroll
    for (int j = 0; j < 6; ++j) {
        xa[j] = srow4[l16*2 + j*32];
        xb[j] = srow4[l16*2 + j*32 + 1];
        double a0 = xa[j].x, a1 = xa[j].y, a2 = xa[j].z, a3 = xa[j].w;
        double a4 = xb[j].x, a5 = xb[j].y, a6 = xb[j].z, a7 = xb[j].w;
        s_ += (a0+a1)+(a2+a3)+((a4+a5)+(a6+a7));
        ss += a0*a0+a1*a1+a2*a2+a3*a3+a4*a4+a5*a5+a6*a6+a7*a7;
    }
    #pragma unroll
    for (int m = 8; m; m >>= 1) { s_ += __shfl_xor(s_, m, 64); ss += __shfl_xor(ss, m, 64); }
    const double mud = s_ / 768.0;
    const float mu = (float)mud;
    const float rs = (float)(1.0 / sqrt(ss / 768.0 - mud*mud + 1e-5));

    // ---- phase B: LN + split-f16, write fragment-ordered swizzled planes
    const int rsz = row & 7;
    #pragma unroll
    for (int j = 0; j < 6; ++j) {
        const int c0 = l16*8 + j*128;
        float4 lw_a = reinterpret_cast<const float4*>(lnw)[l16*2 + j*32];
        float4 lw_b = reinterpret_cast<const float4*>(lnw)[l16*2 + j*32 + 1];
        float4 lb_a = reinterpret_cast<const float4*>(lnb)[l16*2 + j*32];
        float4 lb_b = reinterpret_cast<const float4*>(lnb)[l16*2 + j*32 + 1];
        float xn[8];
        xn[0] = (xa[j].x - mu)*rs*lw_a.x + lb_a.x;
        xn[1] = (xa[j].y - mu)*rs*lw_a.y + lb_a.y;
        xn[2] = (xa[j].z - mu)*rs*lw_a.z + lb_a.z;
        xn[3] = (xa[j].w - mu)*rs*lw_a.w + lb_a.w;
        xn[4] = (xb[j].x - mu)*rs*lw_b.x + lb_b.x;
        xn[5] = (xb[j].y - mu)*rs*lw_b.y + lb_b.y;
        xn[6] = (xb[j].z - mu)*rs*lw_b.z + lb_b.z;
        xn[7] = (xb[j].w - mu)*rs*lw_b.w + lb_b.w;
        H2U h01, h23, h45, h67;
        h01.h = __builtin_amdgcn_cvt_pkrtz(xn[0], xn[1]);
        h23.h = __builtin_amdgcn_cvt_pkrtz(xn[2], xn[3]);
        h45.h = __builtin_amdgcn_cvt_pkrtz(xn[4], xn[5]);
        h67.h = __builtin_amdgcn_cvt_pkrtz(xn[6], xn[7]);
        H2U l01, l23, l45, l67;
        l01.h = __builtin_amdgcn_cvt_pkrtz(xn[0] - (float)h01.h.x, xn[1] - (float)h01.h.y);
        l23.h = __builtin_amdgcn_cvt_pkrtz(xn[2] - (float)h23.h.x, xn[3] - (float)h23.h.y);
        l45.h = __builtin_amdgcn_cvt_pkrtz(xn[4] - (float)h45.h.x, xn[5] - (float)h45.h.y);
        l67.h = __builtin_amdgcn_cvt_pkrtz(xn[6] - (float)h67.h.x, xn[7] - (float)h67.h.y);
        const int idx4 = row*96 + ((c0 >> 3) ^ rsz);
        planes[idx4]        = make_uint4(h01.u, h23.u, h45.u, h67.u);
        planes[1536 + idx4] = make_uint4(l01.u, l23.u, l45.u, l67.u);
    }
    __syncthreads();

    // ---- phase C: barrier-free MFMA loop (A frags from LDS, B from L2)
    const unsigned short* wtp = wt + ((size_t)g*HH + colbase + t16)*8;
    f32x4 acc0 = {0,0,0,0}, acc1 = {0,0,0,0};
    #pragma unroll 4
    for (int s = 0; s < NSTEP; ++s) {
        const int q = ((s*4 + g) ^ t7) + t16*96;
        U4F Ah, Al;
        Ah.u = planes[q];
        Al.u = planes[1536 + q];
        f16x8 B0 = *reinterpret_cast<const f16x8*>(wtp + (size_t)s*4096);
        f16x8 B1 = *reinterpret_cast<const f16x8*>(wtp + (size_t)s*4096 + 128);
        acc0 = __builtin_amdgcn_mfma_f32_16x16x32_f16(Ah.h, B0, acc0, 0, 0, 0);
        acc0 = __builtin_amdgcn_mfma_f32_16x16x32_f16(Al.h, B0, acc0, 0, 0, 0);
        acc1 = __builtin_amdgcn_mfma_f32_16x16x32_f16(Ah.h, B1, acc1, 0, 0, 0);
        acc1 = __builtin_amdgcn_mfma_f32_16x16x32_f16(Al.h, B1, acc1, 0, 0, 0);
    }

    // ---- epilogue: +b1, exact gelu (f32/erff), dot w2, 16-lane reduce
    const float b1A = b1[colbase + t16];
    const float b1B = b1[colbase + 16 + t16];
    const float w2A = w2[colbase + t16];
    const float w2B = w2[colbase + 16 + t16];
    const float is2 = 0.70710678f;

    float psum[4];
    #pragma unroll
    for (int r = 0; r < 4; ++r) {
        float v0 = acc0[r] + b1A;
        float v1 = acc1[r] + b1B;
        float g0 = 0.5f * v0 * (1.0f + erff(v0 * is2));
        float g1 = 0.5f * v1 * (1.0f + erff(v1 * is2));
        float p = g0 * w2A + g1 * w2B;
        #pragma unroll
        for (int m = 8; m; m >>= 1) p += __shfl_xor(p, m, 64);
        psum[r] = p;
    }
    if (t16 == 0) {
        #pragma unroll
        for (int r = 0; r < 4; ++r) part[wave][g*4 + r] = psum[r];
    }
    __syncthreads();
    if (tid < 16) {
        float s = part[0][tid] + part[1][tid] + part[2][tid] + part[3][tid] + b2[0];
        int tok = tok0 + tid;
        sc[tok] = (double)s;
        scores_out[tok] = ((tok % NN) == 0) ? 1.0e9f : s;
    }
}

// ---------------- K3: per-batch bitonic top-k (full 1024 sort) ------
__global__ __launch_bounds__(1024) void k_topk(const double* __restrict__ sc,
                                               float* __restrict__ idx_out)
{
    __shared__ double sk_[1024];
    __shared__ int    si[1024];
    const int tid = threadIdx.x;
    const int b   = blockIdx.x;
    sk_[tid] = sc[b*NN + 1 + tid];
    si[tid] = tid + 1;
    __syncthreads();
    for (int k = 2; k <= 1024; k <<= 1) {
        for (int j = k >> 1; j > 0; j >>= 1) {
            int ixj = tid ^ j;
            if (ixj > tid) {
                double sa = sk_[tid]; int ia = si[tid];
                double sb = sk_[ixj]; int ib = si[ixj];
                bool beforeB = (sb > sa) || (sb == sa && ib < ia);
                bool dirAsc  = ((tid & k) == 0);
                if (beforeB == dirAsc) {
                    sk_[tid] = sb; si[tid] = ib;
                    sk_[ixj] = sa; si[ixj] = ia;
                }
            }
            __syncthreads();
        }
    }
    if (tid == 0)  idx_out[b*(KK+1)] = 0.0f;
    if (tid < KK)  idx_out[b*(KK+1) + 1 + tid] = (float)si[tid];
}

// ---------------- K4: gather selected tokens ------------------------
__global__ __launch_bounds__(192) void k_gather(const float* __restrict__ x,
                                                const float* __restrict__ idx_out,
                                                float* __restrict__ xred)
{
    const int r = blockIdx.x;               // 0 .. 64*257-1
    const int b = r / (KK+1);
    const int idx = (int)(idx_out[r] + 0.5f);
    const float4* src = reinterpret_cast<const float4*>(x + ((size_t)b*NN + idx) * DD);
    float4* dst = reinterpret_cast<float4*>(xred + (size_t)r * DD);
    dst[threadIdx.x] = src[threadIdx.x];
}

extern "C" void kernel_launch(void* const* d_in, const int* in_sizes, int n_in,
                              void* d_out, int out_size, void* d_ws, size_t ws_size,
                              hipStream_t stream)
{
    const float* x   = (const float*)d_in[0];
    const float* lnw = (const float*)d_in[1];
    const float* lnb = (const float*)d_in[2];
    const float* w1  = (const float*)d_in[3];
    const float* b1  = (const float*)d_in[4];
    const float* w2  = (const float*)d_in[5];
    const float* b2  = (const float*)d_in[6];

    float* out   = (float*)d_out;
    float* xred  = out + OUT_XRED;
    float* idxf  = out + OUT_IDX;
    float* scout = out + OUT_SC;

    char* wsb = (char*)d_ws;
    double* sc          = (double*)(wsb);                         // 524,800 B
    unsigned short* wt  = (unsigned short*)(wsb + (size_t)TOK*8); // 196,608 B

    k_cvtw  <<<DD*HH/256, 256, 0, stream>>>(w1, wt);
    k_fused <<<TOK/16, 256, 0, stream>>>(x, lnw, lnb, wt, b1, w2, b2, sc, scout);
    k_topk  <<<BB, 1024, 0, stream>>>(sc, idxf);
    k_gather<<<BB*(KK+1), 192, 0, stream>>>(x, idxf, xred);
}

// Round 8
// 94.825 us; speedup vs baseline: 3.9326x; 1.2981x over previous
//
#include <hip/hip_runtime.h>
#include <hip/hip_bf16.h>
#include <math.h>

#define BB 64
#define NN 1025
#define DD 768
#define HH 128
#define KK 256
#define TOK (BB*NN)          // 65600
#define OUT_XRED 0
#define OUT_IDX  (BB*(KK+1)*DD)            // 12,632,064
#define OUT_SC   (OUT_IDX + BB*(KK+1))     // + 16,448

typedef float    f32x4 __attribute__((ext_vector_type(4)));
typedef __fp16   h16x2 __attribute__((ext_vector_type(2)));
typedef _Float16 f16x8 __attribute__((ext_vector_type(8)));
#define NSTEP (DD/32)        // 24 MFMA k-steps

union U4F { uint4 u; f16x8 h; };
union H2U { h16x2 h; unsigned int u; };

// ---------------- K0: W1 -> f16, MFMA-frag-transposed layout ---------
// wt[((s*4+g)*HH + n)*8 + j] = f16(W1[k = s*32+g*8+j][n])
__global__ __launch_bounds__(256) void k_cvtw(const float* __restrict__ w1,
                                              unsigned short* __restrict__ wt)
{
    int i = blockIdx.x*256 + threadIdx.x;    // 98304 exact
    int k = i >> 7, n = i & 127;
    union { _Float16 h; unsigned short s; } c;
    c.h = (_Float16)w1[i];
    int s = k >> 5, g = (k >> 3) & 3, j = k & 7;
    wt[((s*4 + g)*HH + n)*8 + j] = c.s;
}

// ---------------- K_fused: stats + LN + f16 MFMA + gelu + w2 ---------
// 16 tokens/block, 4 waves, 24 KB LDS -> 6 blocks/CU.
// Phase A: x row -> 48 regs + f32 stats. Phase B: LN -> single f16
// plane, fragment order, row-XOR-swizzled. Phase C: ds_read_b128 ->
// 2 MFMA per k-step. f32 gelu epilogue.
__global__ __launch_bounds__(256) void k_fused(const float* __restrict__ x,
    const float* __restrict__ lnw, const float* __restrict__ lnb,
    const unsigned short* __restrict__ wt,
    const float* __restrict__ b1, const float* __restrict__ w2,
    const float* __restrict__ b2,
    float* __restrict__ scores_out)
{
    __shared__ uint4 planes[16*96];     // 24 KB, single f16 plane
    __shared__ float part[4][16];

    const int tid  = threadIdx.x;
    const int wave = tid >> 6, lane = tid & 63;
    const int g    = lane >> 4, t16 = lane & 15;
    const int t7   = t16 & 7;
    const int tok0 = blockIdx.x * 16;     // grid 4100 exact
    const int colbase = wave * 32;
    const int row = tid >> 4, l16 = tid & 15;

    // ---- phase A: load row into regs, f32 stats
    const float4* srow4 = reinterpret_cast<const float4*>(x + (size_t)(tok0 + row) * DD);
    float4 xa[6], xb[6];
    float s_ = 0.f, ss = 0.f;
    #pragma unroll
    for (int j = 0; j < 6; ++j) {
        xa[j] = srow4[l16*2 + j*32];
        xb[j] = srow4[l16*2 + j*32 + 1];
        s_ += ((xa[j].x + xa[j].y) + (xa[j].z + xa[j].w))
            + ((xb[j].x + xb[j].y) + (xb[j].z + xb[j].w));
        ss += xa[j].x*xa[j].x + xa[j].y*xa[j].y + xa[j].z*xa[j].z + xa[j].w*xa[j].w
            + xb[j].x*xb[j].x + xb[j].y*xb[j].y + xb[j].z*xb[j].z + xb[j].w*xb[j].w;
    }
    #pragma unroll
    for (int m = 8; m; m >>= 1) { s_ += __shfl_xor(s_, m, 64); ss += __shfl_xor(ss, m, 64); }
    const float mu = s_ * (1.0f/768.0f);
    const float rs = 1.0f / sqrtf(ss * (1.0f/768.0f) - mu*mu + 1e-5f);

    // ---- phase B: LN + f16 pack, fragment-ordered swizzled plane
    const int rsz = row & 7;
    #pragma unroll
    for (int j = 0; j < 6; ++j) {
        float4 lw_a = reinterpret_cast<const float4*>(lnw)[l16*2 + j*32];
        float4 lw_b = reinterpret_cast<const float4*>(lnw)[l16*2 + j*32 + 1];
        float4 lb_a = reinterpret_cast<const float4*>(lnb)[l16*2 + j*32];
        float4 lb_b = reinterpret_cast<const float4*>(lnb)[l16*2 + j*32 + 1];
        H2U h01, h23, h45, h67;
        h01.h = __builtin_amdgcn_cvt_pkrtz((xa[j].x - mu)*rs*lw_a.x + lb_a.x,
                                           (xa[j].y - mu)*rs*lw_a.y + lb_a.y);
        h23.h = __builtin_amdgcn_cvt_pkrtz((xa[j].z - mu)*rs*lw_a.z + lb_a.z,
                                           (xa[j].w - mu)*rs*lw_a.w + lb_a.w);
        h45.h = __builtin_amdgcn_cvt_pkrtz((xb[j].x - mu)*rs*lw_b.x + lb_b.x,
                                           (xb[j].y - mu)*rs*lw_b.y + lb_b.y);
        h67.h = __builtin_amdgcn_cvt_pkrtz((xb[j].z - mu)*rs*lw_b.z + lb_b.z,
                                           (xb[j].w - mu)*rs*lw_b.w + lb_b.w);
        planes[row*96 + ((l16 + j*16) ^ rsz)] = make_uint4(h01.u, h23.u, h45.u, h67.u);
    }
    __syncthreads();

    // ---- phase C: barrier-free MFMA loop (A frags from LDS, B from L2)
    const unsigned short* wtp = wt + ((size_t)g*HH + colbase + t16)*8;
    f32x4 acc0 = {0,0,0,0}, acc1 = {0,0,0,0};
    #pragma unroll 4
    for (int s = 0; s < NSTEP; ++s) {
        U4F Ah;
        Ah.u = planes[((s*4 + g) ^ t7) + t16*96];
        f16x8 B0 = *reinterpret_cast<const f16x8*>(wtp + (size_t)s*4096);
        f16x8 B1 = *reinterpret_cast<const f16x8*>(wtp + (size_t)s*4096 + 128);
        acc0 = __builtin_amdgcn_mfma_f32_16x16x32_f16(Ah.h, B0, acc0, 0, 0, 0);
        acc1 = __builtin_amdgcn_mfma_f32_16x16x32_f16(Ah.h, B1, acc1, 0, 0, 0);
    }

    // ---- epilogue: +b1, exact gelu (f32/erff), dot w2, 16-lane reduce
    const float b1A = b1[colbase + t16];
    const float b1B = b1[colbase + 16 + t16];
    const float w2A = w2[colbase + t16];
    const float w2B = w2[colbase + 16 + t16];
    const float is2 = 0.70710678f;

    float psum[4];
    #pragma unroll
    for (int r = 0; r < 4; ++r) {
        float v0 = acc0[r] + b1A;
        float v1 = acc1[r] + b1B;
        float g0 = 0.5f * v0 * (1.0f + erff(v0 * is2));
        float g1 = 0.5f * v1 * (1.0f + erff(v1 * is2));
        float p = g0 * w2A + g1 * w2B;
        #pragma unroll
        for (int m = 8; m; m >>= 1) p += __shfl_xor(p, m, 64);
        psum[r] = p;
    }
    if (t16 == 0) {
        #pragma unroll
        for (int r = 0; r < 4; ++r) part[wave][g*4 + r] = psum[r];
    }
    __syncthreads();
    if (tid < 16) {
        float s = part[0][tid] + part[1][tid] + part[2][tid] + part[3][tid] + b2[0];
        int tok = tok0 + tid;
        scores_out[tok] = ((tok % NN) == 0) ? 1.0e9f : s;
    }
}

// ---------------- K3: per-batch bitonic top-k (full 1024 sort, f32) --
__global__ __launch_bounds__(1024) void k_topk(const float* __restrict__ scores,
                                               float* __restrict__ idx_out)
{
    __shared__ float sk_[1024];
    __shared__ int   si[1024];
    const int tid = threadIdx.x;
    const int b   = blockIdx.x;
    sk_[tid] = scores[b*NN + 1 + tid];
    si[tid] = tid + 1;
    __syncthreads();
    for (int k = 2; k <= 1024; k <<= 1) {
        for (int j = k >> 1; j > 0; j >>= 1) {
            int ixj = tid ^ j;
            if (ixj > tid) {
                float sa = sk_[tid]; int ia = si[tid];
                float sb = sk_[ixj]; int ib = si[ixj];
                bool beforeB = (sb > sa) || (sb == sa && ib < ia);
                bool dirAsc  = ((tid & k) == 0);
                if (beforeB == dirAsc) {
                    sk_[tid] = sb; si[tid] = ib;
                    sk_[ixj] = sa; si[ixj] = ia;
                }
            }
            __syncthreads();
        }
    }
    if (tid == 0)  idx_out[b*(KK+1)] = 0.0f;
    if (tid < KK)  idx_out[b*(KK+1) + 1 + tid] = (float)si[tid];
}

// ---------------- K4: gather selected tokens ------------------------
__global__ __launch_bounds__(192) void k_gather(const float* __restrict__ x,
                                                const float* __restrict__ idx_out,
                                                float* __restrict__ xred)
{
    const int r = blockIdx.x;               // 0 .. 64*257-1
    const int b = r / (KK+1);
    const int idx = (int)(idx_out[r] + 0.5f);
    const float4* src = reinterpret_cast<const float4*>(x + ((size_t)b*NN + idx) * DD);
    float4* dst = reinterpret_cast<float4*>(xred + (size_t)r * DD);
    dst[threadIdx.x] = src[threadIdx.x];
}

extern "C" void kernel_launch(void* const* d_in, const int* in_sizes, int n_in,
                              void* d_out, int out_size, void* d_ws, size_t ws_size,
                              hipStream_t stream)
{
    const float* x   = (const float*)d_in[0];
    const float* lnw = (const float*)d_in[1];
    const float* lnb = (const float*)d_in[2];
    const float* w1  = (const float*)d_in[3];
    const float* b1  = (const float*)d_in[4];
    const float* w2  = (const float*)d_in[5];
    const float* b2  = (const float*)d_in[6];

    float* out   = (float*)d_out;
    float* xred  = out + OUT_XRED;
    float* idxf  = out + OUT_IDX;
    float* scout = out + OUT_SC;

    unsigned short* wt = (unsigned short*)d_ws;   // 196,608 B

    k_cvtw  <<<DD*HH/256, 256, 0, stream>>>(w1, wt);
    k_fused <<<TOK/16, 256, 0, stream>>>(x, lnw, lnb, wt, b1, w2, b2, scout);
    k_topk  <<<BB, 1024, 0, stream>>>(scout, idxf);
    k_gather<<<BB*(KK+1), 192, 0, stream>>>(x, idxf, xred);
}